// Round 5
// baseline (418.450 us; speedup 1.0000x reference)
//
#include <hip/hip_runtime.h>

typedef unsigned short ushort_t;
typedef __bf16 bf16x8 __attribute__((ext_vector_type(8)));
typedef __bf16 bf16x4 __attribute__((ext_vector_type(4)));
typedef float floatx4 __attribute__((ext_vector_type(4)));

__device__ inline ushort_t f2bf(float f) {
    __bf16 h = (__bf16)f;
    return __builtin_bit_cast(ushort_t, h);
}

// ---------------------------------------------------------------- cast x -> bf16
__global__ __launch_bounds__(256) void cast_x_kernel(const float* __restrict__ x,
                                                     ushort_t* __restrict__ o) {
    int i = (blockIdx.x * 256 + threadIdx.x) * 4;
    float4 v = *(const float4*)(x + i);
    ushort4 u;
    u.x = f2bf(v.x); u.y = f2bf(v.y); u.z = f2bf(v.z); u.w = f2bf(v.w);
    *(ushort4*)(o + i) = u;
}

// ------------------------------------------- transpose+cast W[k][n] -> Wt[n][k] bf16
__global__ __launch_bounds__(256) void wt_kernel(const float* __restrict__ W0, const float* __restrict__ W1,
                                                 const float* __restrict__ W2, const float* __restrict__ W3,
                                                 ushort_t* __restrict__ T0, ushort_t* __restrict__ T1,
                                                 ushort_t* __restrict__ T2, ushort_t* __restrict__ T3) {
    __shared__ float t[32][33];
    const float* W; ushort_t* T;
    switch (blockIdx.z) {
        case 0: W = W0; T = T0; break;
        case 1: W = W1; T = T1; break;
        case 2: W = W2; T = T2; break;
        default: W = W3; T = T3; break;
    }
    int n0 = blockIdx.x * 32, k0 = blockIdx.y * 32;
    int tx = threadIdx.x, ty = threadIdx.y;  // 32 x 8
    for (int i = 0; i < 4; ++i)
        t[ty + i * 8][tx] = W[(k0 + ty + i * 8) * 768 + n0 + tx];
    __syncthreads();
    for (int i = 0; i < 4; ++i)
        T[(n0 + ty + i * 8) * 768 + k0 + tx] = f2bf(t[tx][ty + i * 8]);
}

// ---------------------------------------------------------------- fused QKV GEMM
// Q is pre-scaled by 0.125 * log2(e) so attention can use native exp2.
__global__ __launch_bounds__(256) void gemm_qkv(
    const ushort_t* __restrict__ A,
    const ushort_t* __restrict__ Tq, const ushort_t* __restrict__ Tk, const ushort_t* __restrict__ Tv,
    const float* __restrict__ bq, const float* __restrict__ bk, const float* __restrict__ bv,
    ushort_t* __restrict__ Qb, ushort_t* __restrict__ Kb, ushort_t* __restrict__ Vtb) {
    __shared__ ushort_t As[128 * 72];
    __shared__ ushort_t Bs[128 * 72];
    int tid = threadIdx.x;
    int m0 = blockIdx.x * 128;
    int nt = blockIdx.y;       // 0..17
    int which = nt / 6;
    int n0 = (nt % 6) * 128;
    const ushort_t* Bt = which == 0 ? Tq : (which == 1 ? Tk : Tv);
    const float* bias = which == 0 ? bq : (which == 1 ? bk : bv);

    int wave = tid >> 6;
    int ln = tid & 15;
    int quad = (tid >> 4) & 3;
    int wm = (wave & 1) * 64;
    int wn = (wave >> 1) * 64;

    floatx4 acc[4][4];
    floatx4 z = {0.f, 0.f, 0.f, 0.f};
    for (int i = 0; i < 4; ++i)
        for (int j = 0; j < 4; ++j) acc[i][j] = z;

    int srow = tid >> 3;          // 0..31
    int scol = (tid & 7) * 8;     // 0,8,...,56

    for (int kt = 0; kt < 12; ++kt) {
        int k0 = kt * 64;
        for (int p = 0; p < 4; ++p) {
            int r = p * 32 + srow;
            *(float4*)&As[r * 72 + scol] = *(const float4*)&A[(m0 + r) * 768 + k0 + scol];
            *(float4*)&Bs[r * 72 + scol] = *(const float4*)&Bt[(n0 + r) * 768 + k0 + scol];
        }
        __syncthreads();
        for (int ks = 0; ks < 2; ++ks) {
            bf16x8 a[4], b[4];
            for (int i = 0; i < 4; ++i)
                a[i] = *(const bf16x8*)&As[(wm + i * 16 + ln) * 72 + ks * 32 + quad * 8];
            for (int j = 0; j < 4; ++j)
                b[j] = *(const bf16x8*)&Bs[(wn + j * 16 + ln) * 72 + ks * 32 + quad * 8];
            for (int i = 0; i < 4; ++i)
                for (int j = 0; j < 4; ++j)
                    acc[i][j] = __builtin_amdgcn_mfma_f32_16x16x32_bf16(a[i], b[j], acc[i][j], 0, 0, 0);
        }
        __syncthreads();
    }

    const float QSCALE = 0.125f * 1.44269504088896f;  // fold softmax scale * log2(e)
    for (int i = 0; i < 4; ++i) {
        for (int j = 0; j < 4; ++j) {
            int gn = n0 + wn + j * 16 + ln;   // 0..767
            float bia = bias[gn];
            int h = gn >> 6, dd = gn & 63;
            for (int r = 0; r < 4; ++r) {
                int gm = m0 + wm + i * 16 + quad * 4 + r;
                int bb = gm >> 11, ss = gm & 2047;
                float v = acc[i][j][r] + bia;
                if (which == 0) {
                    Qb[((bb * 12 + h) * 2048 + ss) * 64 + dd] = f2bf(v * QSCALE);
                } else if (which == 1) {
                    Kb[((bb * 12 + h) * 2048 + ss) * 64 + dd] = f2bf(v);
                } else {
                    Vtb[((bb * 12 + h) * 64 + dd) * 2048 + ss] = f2bf(v);
                }
            }
        }
    }
}

// ---------------------------------------------------------------- flash attention v3
// Zero-LDS, zero-barrier. Computes S^T = K Q^T (A=K from global, B=Q hoisted),
// exp2 in C-layout, then O^T = V^T P^T where P^T B-frags come straight from
// registers (key order permuted; V^T A-frags loaded in the SAME permuted order
// via two 8B loads — dot products are permutation-invariant in k).
// Wave = 32 q-columns (2 groups of 16). Block = 4 waves = 128 q. No staging.
__global__ __launch_bounds__(256) void attn_kernel(
    const ushort_t* __restrict__ Qb, const ushort_t* __restrict__ Kb,
    const ushort_t* __restrict__ Vtb, ushort_t* __restrict__ Ob) {
    int tid = threadIdx.x;
    int qt = blockIdx.x;   // 0..15
    int bh = blockIdx.y;   // 0..47
    int wave = tid >> 6;   // 0..3
    int ln = tid & 15;
    int quad = (tid >> 4) & 3;
    int q0 = qt * 128 + wave * 32;   // this wave's q base (32 q-columns)

    const ushort_t* Qp = Qb + (size_t)bh * 2048 * 64;
    const ushort_t* Kp = Kb + (size_t)bh * 2048 * 64;
    const ushort_t* Vp = Vtb + (size_t)bh * 64 * 2048;

    // Q B-fragments (loop-invariant): B[k=depth][n=q]
    bf16x8 bqf[2][2];
    for (int g = 0; g < 2; ++g)
        for (int ks = 0; ks < 2; ++ks)
            bqf[g][ks] = *(const bf16x8*)&Qp[(q0 + g * 16 + ln) * 64 + ks * 32 + quad * 8];

    floatx4 o_acc[2][4];   // [g][m4]: O^T[d = m4*16 + quad*4 + r][q = q0 + g*16 + ln]
    float lsum[2] = {0.f, 0.f};
    floatx4 z = {0.f, 0.f, 0.f, 0.f};
    for (int g = 0; g < 2; ++g)
        for (int m4 = 0; m4 < 4; ++m4) o_acc[g][m4] = z;

    for (int kt = 0; kt < 32; ++kt) {
        const ushort_t* Kt = Kp + kt * 64 * 64;
        const ushort_t* Vt = Vp + kt * 64;

        // K A-frags: A[m=key][k=depth], 16B contiguous per lane
        bf16x8 ak[4][2];
        for (int m4 = 0; m4 < 4; ++m4)
            for (int ks = 0; ks < 2; ++ks)
                ak[m4][ks] = *(const bf16x8*)&Kt[(m4 * 16 + ln) * 64 + ks * 32 + quad * 8];

        // V^T A-frags in permuted key order sigma(quad,j) = (j>=4)*16 + quad*4 + (j&3)
        bf16x8 av[4][2];
        for (int m4 = 0; m4 < 4; ++m4)
            for (int c = 0; c < 2; ++c) {
                const ushort_t* vb = &Vt[(m4 * 16 + ln) * 2048 + c * 32 + quad * 4];
                bf16x4 lo = *(const bf16x4*)vb;
                bf16x4 hi = *(const bf16x4*)(vb + 16);
                bf16x8 a;
                a[0] = lo[0]; a[1] = lo[1]; a[2] = lo[2]; a[3] = lo[3];
                a[4] = hi[0]; a[5] = hi[1]; a[6] = hi[2]; a[7] = hi[3];
                av[m4][c] = a;
            }

        // S^T = K Q^T : st[g][m4] at (key = m4*16 + quad*4 + r, q = q0 + g*16 + ln)
        floatx4 st[2][4];
        for (int g = 0; g < 2; ++g)
            for (int m4 = 0; m4 < 4; ++m4) {
                floatx4 s = z;
                s = __builtin_amdgcn_mfma_f32_16x16x32_bf16(ak[m4][0], bqf[g][0], s, 0, 0, 0);
                s = __builtin_amdgcn_mfma_f32_16x16x32_bf16(ak[m4][1], bqf[g][1], s, 0, 0, 0);
                st[g][m4] = s;
            }

        // P^T = 2^(S^T)  (Q pre-scaled by 0.125*log2e); per-lane row... column sums
        float p[2][4][4];
        for (int g = 0; g < 2; ++g)
            for (int m4 = 0; m4 < 4; ++m4)
                for (int r = 0; r < 4; ++r) {
                    float pv = __builtin_amdgcn_exp2f(st[g][m4][r]);
                    p[g][m4][r] = pv;
                    lsum[g] += pv;
                }

        // Pack P^T B-frags: reg j<4 <- block 2c reg j ; j>=4 <- block 2c+1 reg j-4
        // (key order matches av's sigma permutation)
        for (int g = 0; g < 2; ++g) {
            bf16x8 bp[2];
            for (int c = 0; c < 2; ++c) {
                bf16x8 bpp;
                bpp[0] = (__bf16)p[g][2 * c][0];
                bpp[1] = (__bf16)p[g][2 * c][1];
                bpp[2] = (__bf16)p[g][2 * c][2];
                bpp[3] = (__bf16)p[g][2 * c][3];
                bpp[4] = (__bf16)p[g][2 * c + 1][0];
                bpp[5] = (__bf16)p[g][2 * c + 1][1];
                bpp[6] = (__bf16)p[g][2 * c + 1][2];
                bpp[7] = (__bf16)p[g][2 * c + 1][3];
                bp[c] = bpp;
            }
            for (int m4 = 0; m4 < 4; ++m4)
                for (int c = 0; c < 2; ++c)
                    o_acc[g][m4] = __builtin_amdgcn_mfma_f32_16x16x32_bf16(av[m4][c], bp[c], o_acc[g][m4], 0, 0, 0);
        }
    }

    // column sums: combine the 4 quads (lane&15 preserved)
    for (int g = 0; g < 2; ++g) {
        lsum[g] += __shfl_xor(lsum[g], 16);
        lsum[g] += __shfl_xor(lsum[g], 32);
    }

    int b = bh / 12, h = bh % 12;
    for (int g = 0; g < 2; ++g) {
        float inv = 1.f / lsum[g];
        int token = b * 2048 + q0 + g * 16 + ln;
        for (int m4 = 0; m4 < 4; ++m4)
            for (int r = 0; r < 4; ++r)
                Ob[token * 768 + h * 64 + m4 * 16 + quad * 4 + r] = f2bf(o_acc[g][m4][r] * inv);
    }
}

// ---------------------------------------------------------------- output projection (fp32 out)
__global__ __launch_bounds__(256) void gemm_out(
    const ushort_t* __restrict__ A, const ushort_t* __restrict__ Bt,
    const float* __restrict__ bias, float* __restrict__ out) {
    __shared__ ushort_t As[128 * 72];
    __shared__ ushort_t Bs[128 * 72];
    int tid = threadIdx.x;
    int m0 = blockIdx.x * 128;
    int n0 = blockIdx.y * 128;

    int wave = tid >> 6;
    int ln = tid & 15;
    int quad = (tid >> 4) & 3;
    int wm = (wave & 1) * 64;
    int wn = (wave >> 1) * 64;

    floatx4 acc[4][4];
    floatx4 z = {0.f, 0.f, 0.f, 0.f};
    for (int i = 0; i < 4; ++i)
        for (int j = 0; j < 4; ++j) acc[i][j] = z;

    int srow = tid >> 3;
    int scol = (tid & 7) * 8;

    for (int kt = 0; kt < 12; ++kt) {
        int k0 = kt * 64;
        for (int p = 0; p < 4; ++p) {
            int r = p * 32 + srow;
            *(float4*)&As[r * 72 + scol] = *(const float4*)&A[(m0 + r) * 768 + k0 + scol];
            *(float4*)&Bs[r * 72 + scol] = *(const float4*)&Bt[(n0 + r) * 768 + k0 + scol];
        }
        __syncthreads();
        for (int ks = 0; ks < 2; ++ks) {
            bf16x8 a[4], b[4];
            for (int i = 0; i < 4; ++i)
                a[i] = *(const bf16x8*)&As[(wm + i * 16 + ln) * 72 + ks * 32 + quad * 8];
            for (int j = 0; j < 4; ++j)
                b[j] = *(const bf16x8*)&Bs[(wn + j * 16 + ln) * 72 + ks * 32 + quad * 8];
            for (int i = 0; i < 4; ++i)
                for (int j = 0; j < 4; ++j)
                    acc[i][j] = __builtin_amdgcn_mfma_f32_16x16x32_bf16(a[i], b[j], acc[i][j], 0, 0, 0);
        }
        __syncthreads();
    }

    for (int i = 0; i < 4; ++i) {
        for (int j = 0; j < 4; ++j) {
            int gn = n0 + wn + j * 16 + ln;
            float bia = bias[gn];
            for (int r = 0; r < 4; ++r) {
                int gm = m0 + wm + i * 16 + quad * 4 + r;
                out[gm * 768 + gn] = acc[i][j][r] + bia;
            }
        }
    }
}

extern "C" void kernel_launch(void* const* d_in, const int* in_sizes, int n_in,
                              void* d_out, int out_size, void* d_ws, size_t ws_size,
                              hipStream_t stream) {
    const float* x  = (const float*)d_in[0];
    const float* Wq = (const float*)d_in[1];
    const float* bq = (const float*)d_in[2];
    const float* Wk = (const float*)d_in[3];
    const float* bk = (const float*)d_in[4];
    const float* Wv = (const float*)d_in[5];
    const float* bv = (const float*)d_in[6];
    const float* Wo = (const float*)d_in[7];
    const float* bo = (const float*)d_in[8];

    const int NTOK = 4 * 2048;        // 8192
    const int NELT = NTOK * 768;      // 6291456
    const int WELT = 768 * 768;       // 589824

    ushort_t* xbf = (ushort_t*)d_ws;
    ushort_t* Tq  = xbf + NELT;
    ushort_t* Tk  = Tq + WELT;
    ushort_t* Tv  = Tk + WELT;
    ushort_t* To  = Tv + WELT;
    ushort_t* Qb  = To + WELT;
    ushort_t* Kb  = Qb + NELT;
    ushort_t* Vtb = Kb + NELT;
    ushort_t* Ob  = Vtb + NELT;

    cast_x_kernel<<<NELT / 1024, 256, 0, stream>>>(x, xbf);
    wt_kernel<<<dim3(24, 24, 4), dim3(32, 8), 0, stream>>>(Wq, Wk, Wv, Wo, Tq, Tk, Tv, To);
    gemm_qkv<<<dim3(64, 18), 256, 0, stream>>>(xbf, Tq, Tk, Tv, bq, bk, bv, Qb, Kb, Vtb);
    attn_kernel<<<dim3(16, 48), 256, 0, stream>>>(Qb, Kb, Vtb, Ob);
    gemm_out<<<dim3(64, 6), 256, 0, stream>>>(Ob, To, bo, (float*)d_out);
}

// Round 6
// 282.327 us; speedup vs baseline: 1.4821x; 1.4821x over previous
//
#include <hip/hip_runtime.h>

typedef unsigned short ushort_t;
typedef __bf16 bf16x8 __attribute__((ext_vector_type(8)));
typedef float floatx4 __attribute__((ext_vector_type(4)));

__device__ inline ushort_t f2bf(float f) {
    __bf16 h = (__bf16)f;
    return __builtin_bit_cast(ushort_t, h);
}

// ---------------------------------------------------------------- cast x -> bf16
__global__ __launch_bounds__(256) void cast_x_kernel(const float* __restrict__ x,
                                                     ushort_t* __restrict__ o) {
    int i = (blockIdx.x * 256 + threadIdx.x) * 4;
    float4 v = *(const float4*)(x + i);
    ushort4 u;
    u.x = f2bf(v.x); u.y = f2bf(v.y); u.z = f2bf(v.z); u.w = f2bf(v.w);
    *(ushort4*)(o + i) = u;
}

// ------------------------------------------- transpose+cast W[k][n] -> Wt[n][k] bf16
__global__ __launch_bounds__(256) void wt_kernel(const float* __restrict__ W0, const float* __restrict__ W1,
                                                 const float* __restrict__ W2, const float* __restrict__ W3,
                                                 ushort_t* __restrict__ T0, ushort_t* __restrict__ T1,
                                                 ushort_t* __restrict__ T2, ushort_t* __restrict__ T3) {
    __shared__ float t[32][33];
    const float* W; ushort_t* T;
    switch (blockIdx.z) {
        case 0: W = W0; T = T0; break;
        case 1: W = W1; T = T1; break;
        case 2: W = W2; T = T2; break;
        default: W = W3; T = T3; break;
    }
    int n0 = blockIdx.x * 32, k0 = blockIdx.y * 32;
    int tx = threadIdx.x, ty = threadIdx.y;  // 32 x 8
    for (int i = 0; i < 4; ++i)
        t[ty + i * 8][tx] = W[(k0 + ty + i * 8) * 768 + n0 + tx];
    __syncthreads();
    for (int i = 0; i < 4; ++i)
        T[(n0 + ty + i * 8) * 768 + k0 + tx] = f2bf(t[tx][ty + i * 8]);
}

// ---------------------------------------------------------------- fused QKV GEMM
// Q is pre-scaled by 0.125 * log2(e) so attention can use native exp2.
__global__ __launch_bounds__(256) void gemm_qkv(
    const ushort_t* __restrict__ A,
    const ushort_t* __restrict__ Tq, const ushort_t* __restrict__ Tk, const ushort_t* __restrict__ Tv,
    const float* __restrict__ bq, const float* __restrict__ bk, const float* __restrict__ bv,
    ushort_t* __restrict__ Qb, ushort_t* __restrict__ Kb, ushort_t* __restrict__ Vtb) {
    __shared__ ushort_t As[128 * 72];
    __shared__ ushort_t Bs[128 * 72];
    int tid = threadIdx.x;
    int m0 = blockIdx.x * 128;
    int nt = blockIdx.y;       // 0..17
    int which = nt / 6;
    int n0 = (nt % 6) * 128;
    const ushort_t* Bt = which == 0 ? Tq : (which == 1 ? Tk : Tv);
    const float* bias = which == 0 ? bq : (which == 1 ? bk : bv);

    int wave = tid >> 6;
    int ln = tid & 15;
    int quad = (tid >> 4) & 3;
    int wm = (wave & 1) * 64;
    int wn = (wave >> 1) * 64;

    floatx4 acc[4][4];
    floatx4 z = {0.f, 0.f, 0.f, 0.f};
    for (int i = 0; i < 4; ++i)
        for (int j = 0; j < 4; ++j) acc[i][j] = z;

    int srow = tid >> 3;          // 0..31
    int scol = (tid & 7) * 8;     // 0,8,...,56

    for (int kt = 0; kt < 12; ++kt) {
        int k0 = kt * 64;
        for (int p = 0; p < 4; ++p) {
            int r = p * 32 + srow;
            *(float4*)&As[r * 72 + scol] = *(const float4*)&A[(m0 + r) * 768 + k0 + scol];
            *(float4*)&Bs[r * 72 + scol] = *(const float4*)&Bt[(n0 + r) * 768 + k0 + scol];
        }
        __syncthreads();
        for (int ks = 0; ks < 2; ++ks) {
            bf16x8 a[4], b[4];
            for (int i = 0; i < 4; ++i)
                a[i] = *(const bf16x8*)&As[(wm + i * 16 + ln) * 72 + ks * 32 + quad * 8];
            for (int j = 0; j < 4; ++j)
                b[j] = *(const bf16x8*)&Bs[(wn + j * 16 + ln) * 72 + ks * 32 + quad * 8];
            for (int i = 0; i < 4; ++i)
                for (int j = 0; j < 4; ++j)
                    acc[i][j] = __builtin_amdgcn_mfma_f32_16x16x32_bf16(a[i], b[j], acc[i][j], 0, 0, 0);
        }
        __syncthreads();
    }

    const float QSCALE = 0.125f * 1.44269504088896f;  // fold softmax scale * log2(e)
    for (int i = 0; i < 4; ++i) {
        for (int j = 0; j < 4; ++j) {
            int gn = n0 + wn + j * 16 + ln;   // 0..767
            float bia = bias[gn];
            int h = gn >> 6, dd = gn & 63;
            for (int r = 0; r < 4; ++r) {
                int gm = m0 + wm + i * 16 + quad * 4 + r;
                int bb = gm >> 11, ss = gm & 2047;
                float v = acc[i][j][r] + bia;
                if (which == 0) {
                    Qb[((bb * 12 + h) * 2048 + ss) * 64 + dd] = f2bf(v * QSCALE);
                } else if (which == 1) {
                    Kb[((bb * 12 + h) * 2048 + ss) * 64 + dd] = f2bf(v);
                } else {
                    Vtb[((bb * 12 + h) * 64 + dd) * 2048 + ss] = f2bf(v);
                }
            }
        }
    }
}

// ---------------------------------------------------------------- flash attention v4
// S^T = K Q^T (K A-frags from LDS, Q B-frags hoisted in registers); P = exp2(S^T)
// stays in registers and is packed directly into PV B-frags (sigma key
// permutation); V^T staged into LDS PRE-PERMUTED so its A-frags are contiguous
// ds_read_b128. No Ps round-trip, no per-iter reductions. 128 keys/outer-iter
// (two 64-key halves) -> 2 barriers per 128 keys.
__global__ __launch_bounds__(256) void attn_kernel(
    const ushort_t* __restrict__ Qb, const ushort_t* __restrict__ Kb,
    const ushort_t* __restrict__ Vtb, ushort_t* __restrict__ Ob) {
    __shared__ ushort_t Ks[128 * 72];
    __shared__ ushort_t Vs[2 * 64 * 72];   // two 64-key panels, permuted key order
    int tid = threadIdx.x;
    int qt = blockIdx.x;   // 0..15
    int bh = blockIdx.y;   // 0..47
    int wave = tid >> 6;   // 0..3
    int ln = tid & 15;
    int quad = (tid >> 4) & 3;
    int q0 = qt * 128 + wave * 32;   // this wave's 32 q-columns

    const ushort_t* Qp = Qb + (size_t)bh * 2048 * 64;
    const ushort_t* Kp = Kb + (size_t)bh * 2048 * 64;
    const ushort_t* Vp = Vtb + (size_t)bh * 64 * 2048;

    // Q B-fragments (loop-invariant): B[k=depth][n=q]
    bf16x8 bqf[2][2];
    for (int g = 0; g < 2; ++g)
        for (int ks = 0; ks < 2; ++ks)
            bqf[g][ks] = *(const bf16x8*)&Qp[(q0 + g * 16 + ln) * 64 + ks * 32 + quad * 8];

    // staging indices
    int srow = tid >> 3;          // 0..31
    int scol = (tid & 7) * 8;
    int ct = tid & 15;            // V column group (8 keys each)
    int panel = ct >> 3;
    int cc = (ct >> 2) & 1;
    int t0 = (ct & 3) * 8;        // 0,8,16,24 within 32-key group
    int spanA = ((t0 & 8) ? 16 : 0) + ((t0 & 16) ? 4 : 0);
    int vcol = cc * 32 + spanA;
    int drow = tid >> 4;          // 0..15
    ushort_t* VsP = &Vs[panel * 64 * 72];

    floatx4 o_acc[2][4];   // [g][m4]: O^T[d = m4*16+quad*4+r][q = q0+g*16+ln]
    float lsum[2] = {0.f, 0.f};
    floatx4 z = {0.f, 0.f, 0.f, 0.f};
    for (int g = 0; g < 2; ++g)
        for (int m4 = 0; m4 < 4; ++m4) o_acc[g][m4] = z;

    for (int kt = 0; kt < 16; ++kt) {
        __syncthreads();   // previous iteration's reads done
        // K: 128 keys x 64 depth, row-major, coalesced b128
        for (int p = 0; p < 4; ++p) {
            int r = p * 32 + srow;
            *(float4*)&Ks[r * 72 + scol] = *(const float4*)&Kp[(kt * 128 + r) * 64 + scol];
        }
        // V^T: 64 d x 128 keys, written permuted (two b64 per 16B read)
        for (int p = 0; p < 4; ++p) {
            int d = p * 16 + drow;
            uint4 v = *(const uint4*)&Vp[d * 2048 + kt * 128 + ct * 8];
            *(uint2*)&VsP[d * 72 + vcol] = make_uint2(v.x, v.y);
            *(uint2*)&VsP[d * 72 + vcol + 8] = make_uint2(v.z, v.w);
        }
        __syncthreads();

        for (int h = 0; h < 2; ++h) {
            const ushort_t* KsH = &Ks[h * 64 * 72];
            const ushort_t* VsH = &Vs[h * 64 * 72];

            // K A-frags: A[m=key][k=depth]
            bf16x8 ak[4][2];
            for (int m4 = 0; m4 < 4; ++m4)
                for (int ks = 0; ks < 2; ++ks)
                    ak[m4][ks] = *(const bf16x8*)&KsH[(m4 * 16 + ln) * 72 + ks * 32 + quad * 8];

            // S^T = K Q^T : (key = m4*16+quad*4+r, q = q0+g*16+ln)
            floatx4 st[2][4];
            for (int g = 0; g < 2; ++g)
                for (int m4 = 0; m4 < 4; ++m4) {
                    floatx4 s = z;
                    s = __builtin_amdgcn_mfma_f32_16x16x32_bf16(ak[m4][0], bqf[g][0], s, 0, 0, 0);
                    s = __builtin_amdgcn_mfma_f32_16x16x32_bf16(ak[m4][1], bqf[g][1], s, 0, 0, 0);
                    st[g][m4] = s;
                }

            // P^T = 2^(S^T); per-lane column partial sums
            float pv[2][4][4];
            for (int g = 0; g < 2; ++g)
                for (int m4 = 0; m4 < 4; ++m4)
                    for (int r = 0; r < 4; ++r) {
                        float e = __builtin_amdgcn_exp2f(st[g][m4][r]);
                        pv[g][m4][r] = e;
                        lsum[g] += e;
                    }

            // V^T A-frags (pre-permuted in LDS, contiguous b128)
            bf16x8 av[4][2];
            for (int m4 = 0; m4 < 4; ++m4)
                for (int c = 0; c < 2; ++c)
                    av[m4][c] = *(const bf16x8*)&VsH[(m4 * 16 + ln) * 72 + c * 32 + quad * 8];

            // Pack P^T B-frags (key order matches sigma) and accumulate O^T
            for (int g = 0; g < 2; ++g) {
                bf16x8 bp[2];
                for (int c = 0; c < 2; ++c) {
                    bf16x8 b;
                    b[0] = (__bf16)pv[g][2 * c][0];
                    b[1] = (__bf16)pv[g][2 * c][1];
                    b[2] = (__bf16)pv[g][2 * c][2];
                    b[3] = (__bf16)pv[g][2 * c][3];
                    b[4] = (__bf16)pv[g][2 * c + 1][0];
                    b[5] = (__bf16)pv[g][2 * c + 1][1];
                    b[6] = (__bf16)pv[g][2 * c + 1][2];
                    b[7] = (__bf16)pv[g][2 * c + 1][3];
                    bp[c] = b;
                }
                for (int m4 = 0; m4 < 4; ++m4)
                    for (int c = 0; c < 2; ++c)
                        o_acc[g][m4] = __builtin_amdgcn_mfma_f32_16x16x32_bf16(av[m4][c], bp[c], o_acc[g][m4], 0, 0, 0);
            }
        }
    }

    // column sums: combine the 4 quads (lane&15 preserved)
    for (int g = 0; g < 2; ++g) {
        lsum[g] += __shfl_xor(lsum[g], 16);
        lsum[g] += __shfl_xor(lsum[g], 32);
    }

    int b = bh / 12, h = bh % 12;
    for (int g = 0; g < 2; ++g) {
        float inv = 1.f / lsum[g];
        int token = b * 2048 + q0 + g * 16 + ln;
        for (int m4 = 0; m4 < 4; ++m4)
            for (int r = 0; r < 4; ++r)
                Ob[token * 768 + h * 64 + m4 * 16 + quad * 4 + r] = f2bf(o_acc[g][m4][r] * inv);
    }
}

// ---------------------------------------------------------------- output projection (fp32 out)
__global__ __launch_bounds__(256) void gemm_out(
    const ushort_t* __restrict__ A, const ushort_t* __restrict__ Bt,
    const float* __restrict__ bias, float* __restrict__ out) {
    __shared__ ushort_t As[128 * 72];
    __shared__ ushort_t Bs[128 * 72];
    int tid = threadIdx.x;
    int m0 = blockIdx.x * 128;
    int n0 = blockIdx.y * 128;

    int wave = tid >> 6;
    int ln = tid & 15;
    int quad = (tid >> 4) & 3;
    int wm = (wave & 1) * 64;
    int wn = (wave >> 1) * 64;

    floatx4 acc[4][4];
    floatx4 z = {0.f, 0.f, 0.f, 0.f};
    for (int i = 0; i < 4; ++i)
        for (int j = 0; j < 4; ++j) acc[i][j] = z;

    int srow = tid >> 3;
    int scol = (tid & 7) * 8;

    for (int kt = 0; kt < 12; ++kt) {
        int k0 = kt * 64;
        for (int p = 0; p < 4; ++p) {
            int r = p * 32 + srow;
            *(float4*)&As[r * 72 + scol] = *(const float4*)&A[(m0 + r) * 768 + k0 + scol];
            *(float4*)&Bs[r * 72 + scol] = *(const float4*)&Bt[(n0 + r) * 768 + k0 + scol];
        }
        __syncthreads();
        for (int ks = 0; ks < 2; ++ks) {
            bf16x8 a[4], b[4];
            for (int i = 0; i < 4; ++i)
                a[i] = *(const bf16x8*)&As[(wm + i * 16 + ln) * 72 + ks * 32 + quad * 8];
            for (int j = 0; j < 4; ++j)
                b[j] = *(const bf16x8*)&Bs[(wn + j * 16 + ln) * 72 + ks * 32 + quad * 8];
            for (int i = 0; i < 4; ++i)
                for (int j = 0; j < 4; ++j)
                    acc[i][j] = __builtin_amdgcn_mfma_f32_16x16x32_bf16(a[i], b[j], acc[i][j], 0, 0, 0);
        }
        __syncthreads();
    }

    for (int i = 0; i < 4; ++i) {
        for (int j = 0; j < 4; ++j) {
            int gn = n0 + wn + j * 16 + ln;
            float bia = bias[gn];
            for (int r = 0; r < 4; ++r) {
                int gm = m0 + wm + i * 16 + quad * 4 + r;
                out[gm * 768 + gn] = acc[i][j][r] + bia;
            }
        }
    }
}

extern "C" void kernel_launch(void* const* d_in, const int* in_sizes, int n_in,
                              void* d_out, int out_size, void* d_ws, size_t ws_size,
                              hipStream_t stream) {
    const float* x  = (const float*)d_in[0];
    const float* Wq = (const float*)d_in[1];
    const float* bq = (const float*)d_in[2];
    const float* Wk = (const float*)d_in[3];
    const float* bk = (const float*)d_in[4];
    const float* Wv = (const float*)d_in[5];
    const float* bv = (const float*)d_in[6];
    const float* Wo = (const float*)d_in[7];
    const float* bo = (const float*)d_in[8];

    const int NTOK = 4 * 2048;        // 8192
    const int NELT = NTOK * 768;      // 6291456
    const int WELT = 768 * 768;       // 589824

    ushort_t* xbf = (ushort_t*)d_ws;
    ushort_t* Tq  = xbf + NELT;
    ushort_t* Tk  = Tq + WELT;
    ushort_t* Tv  = Tk + WELT;
    ushort_t* To  = Tv + WELT;
    ushort_t* Qb  = To + WELT;
    ushort_t* Kb  = Qb + NELT;
    ushort_t* Vtb = Kb + NELT;
    ushort_t* Ob  = Vtb + NELT;

    cast_x_kernel<<<NELT / 1024, 256, 0, stream>>>(x, xbf);
    wt_kernel<<<dim3(24, 24, 4), dim3(32, 8), 0, stream>>>(Wq, Wk, Wv, Wo, Tq, Tk, Tv, To);
    gemm_qkv<<<dim3(64, 18), 256, 0, stream>>>(xbf, Tq, Tk, Tv, bq, bk, bv, Qb, Kb, Vtb);
    attn_kernel<<<dim3(16, 48), 256, 0, stream>>>(Qb, Kb, Vtb, Ob);
    gemm_out<<<dim3(64, 6), 256, 0, stream>>>(Ob, To, bo, (float*)d_out);
}

// Round 7
// 235.285 us; speedup vs baseline: 1.7785x; 1.1999x over previous
//
#include <hip/hip_runtime.h>

typedef unsigned short ushort_t;
typedef __bf16 bf16x8 __attribute__((ext_vector_type(8)));
typedef float floatx4 __attribute__((ext_vector_type(4)));

__device__ inline ushort_t f2bf(float f) {
    __bf16 h = (__bf16)f;
    return __builtin_bit_cast(ushort_t, h);
}

__device__ inline void gload16(const void* g, void* l) {
    __builtin_amdgcn_global_load_lds((const __attribute__((address_space(1))) void*)g,
                                     (__attribute__((address_space(3))) void*)l, 16, 0, 0);
}

// ---------------------------------------------------------------- cast x -> bf16
__global__ __launch_bounds__(256) void cast_x_kernel(const float* __restrict__ x,
                                                     ushort_t* __restrict__ o) {
    int i = (blockIdx.x * 256 + threadIdx.x) * 4;
    float4 v = *(const float4*)(x + i);
    ushort4 u;
    u.x = f2bf(v.x); u.y = f2bf(v.y); u.z = f2bf(v.z); u.w = f2bf(v.w);
    *(ushort4*)(o + i) = u;
}

// ------------------------------------------- transpose+cast W[k][n] -> Wt[n][k] bf16
__global__ __launch_bounds__(256) void wt_kernel(const float* __restrict__ W0, const float* __restrict__ W1,
                                                 const float* __restrict__ W2, const float* __restrict__ W3,
                                                 ushort_t* __restrict__ T0, ushort_t* __restrict__ T1,
                                                 ushort_t* __restrict__ T2, ushort_t* __restrict__ T3) {
    __shared__ float t[32][33];
    const float* W; ushort_t* T;
    switch (blockIdx.z) {
        case 0: W = W0; T = T0; break;
        case 1: W = W1; T = T1; break;
        case 2: W = W2; T = T2; break;
        default: W = W3; T = T3; break;
    }
    int n0 = blockIdx.x * 32, k0 = blockIdx.y * 32;
    int tx = threadIdx.x, ty = threadIdx.y;  // 32 x 8
    for (int i = 0; i < 4; ++i)
        t[ty + i * 8][tx] = W[(k0 + ty + i * 8) * 768 + n0 + tx];
    __syncthreads();
    for (int i = 0; i < 4; ++i)
        T[(n0 + ty + i * 8) * 768 + k0 + tx] = f2bf(t[tx][ty + i * 8]);
}

// ---------------------------------------------------------------- fused QKV GEMM (m97-style staging)
// Q is pre-scaled by 0.125 * log2(e) so attention can use native exp2.
__global__ __launch_bounds__(256) void gemm_qkv(
    const ushort_t* __restrict__ A,
    const ushort_t* __restrict__ Tq, const ushort_t* __restrict__ Tk, const ushort_t* __restrict__ Tv,
    const float* __restrict__ bq, const float* __restrict__ bk, const float* __restrict__ bv,
    ushort_t* __restrict__ Qb, ushort_t* __restrict__ Kb, ushort_t* __restrict__ Vtb) {
    __shared__ ushort_t As[128 * 64];
    __shared__ ushort_t Bs[128 * 64];
    int tid = threadIdx.x;
    int m0 = blockIdx.x * 128;
    int nt = blockIdx.y;       // 0..17
    int which = nt / 6;
    int n0 = (nt % 6) * 128;
    const ushort_t* Bt = which == 0 ? Tq : (which == 1 ? Tk : Tv);
    const float* bias = which == 0 ? bq : (which == 1 ? bk : bv);

    int wave = tid >> 6;
    int lane = tid & 63;
    int ln = tid & 15;
    int quad = (tid >> 4) & 3;
    int wm = (wave & 1) * 64;
    int wn = (wave >> 1) * 64;
    int lr = lane >> 3;          // 0..7
    int lc = (lane & 7) * 8;     // element col in 64

    floatx4 acc[4][4];
    floatx4 z = {0.f, 0.f, 0.f, 0.f};
    for (int i = 0; i < 4; ++i)
        for (int j = 0; j < 4; ++j) acc[i][j] = z;

    for (int kt = 0; kt < 12; ++kt) {
        int k0 = kt * 64;
        __syncthreads();
        for (int i = 0; i < 4; ++i) {
            int c = wave * 4 + i;        // chunk 0..15, rows 8c..8c+7
            int row = c * 8 + lr;
            gload16(&A[(m0 + row) * 768 + k0 + lc], &As[c * 512]);
            gload16(&Bt[(n0 + row) * 768 + k0 + lc], &Bs[c * 512]);
        }
        __syncthreads();
        for (int ks = 0; ks < 2; ++ks) {
            bf16x8 a[4], b[4];
            for (int i = 0; i < 4; ++i)
                a[i] = *(const bf16x8*)&As[(wm + i * 16 + ln) * 64 + ks * 32 + quad * 8];
            for (int j = 0; j < 4; ++j)
                b[j] = *(const bf16x8*)&Bs[(wn + j * 16 + ln) * 64 + ks * 32 + quad * 8];
            for (int i = 0; i < 4; ++i)
                for (int j = 0; j < 4; ++j)
                    acc[i][j] = __builtin_amdgcn_mfma_f32_16x16x32_bf16(a[i], b[j], acc[i][j], 0, 0, 0);
        }
    }

    const float QSCALE = 0.125f * 1.44269504088896f;  // fold softmax scale * log2(e)
    for (int i = 0; i < 4; ++i) {
        for (int j = 0; j < 4; ++j) {
            int gn = n0 + wn + j * 16 + ln;   // 0..767
            float bia = bias[gn];
            int h = gn >> 6, dd = gn & 63;
            for (int r = 0; r < 4; ++r) {
                int gm = m0 + wm + i * 16 + quad * 4 + r;
                int bb = gm >> 11, ss = gm & 2047;
                float v = acc[i][j][r] + bia;
                if (which == 0) {
                    Qb[((bb * 12 + h) * 2048 + ss) * 64 + dd] = f2bf(v * QSCALE);
                } else if (which == 1) {
                    Kb[((bb * 12 + h) * 2048 + ss) * 64 + dd] = f2bf(v);
                } else {
                    Vtb[((bb * 12 + h) * 64 + dd) * 2048 + ss] = f2bf(v);
                }
            }
        }
    }
}

// ---------------------------------------------------------------- flash attention v5
// Double-buffered 64-key panels, ONE barrier per iter. Global loads for panel
// t+1 issued before computing panel t (latency hidden); regs written to the
// other buffer after compute. S^T = K Q^T (Q B-frags hoisted); P = exp2 stays
// in registers, packed into PV B-frags with the sigma key permutation; V^T
// staged pre-permuted so its A-frags are contiguous b128.
__global__ __launch_bounds__(256) void attn_kernel(
    const ushort_t* __restrict__ Qb, const ushort_t* __restrict__ Kb,
    const ushort_t* __restrict__ Vtb, ushort_t* __restrict__ Ob) {
    __shared__ ushort_t Ks[2][64 * 72];
    __shared__ ushort_t Vs[2][64 * 72];
    int tid = threadIdx.x;
    int qt = blockIdx.x;   // 0..15
    int bh = blockIdx.y;   // 0..47
    int wave = tid >> 6;   // 0..3
    int ln = tid & 15;
    int quad = (tid >> 4) & 3;
    int q0 = qt * 128 + wave * 32;   // this wave's 32 q-columns

    const ushort_t* Qp = Qb + (size_t)bh * 2048 * 64;
    const ushort_t* Kp = Kb + (size_t)bh * 2048 * 64;
    const ushort_t* Vp = Vtb + (size_t)bh * 64 * 2048;

    // Q B-fragments (loop-invariant)
    bf16x8 bqf[2][2];
    for (int g = 0; g < 2; ++g)
        for (int ks = 0; ks < 2; ++ks)
            bqf[g][ks] = *(const bf16x8*)&Qp[(q0 + g * 16 + ln) * 64 + ks * 32 + quad * 8];

    // staging indices
    int srow = tid >> 3;            // 0..31 (K rows / V d-rows)
    int c8 = tid & 7;               // 16B chunk within 64 keys
    int scol = c8 * 8;
    int u = c8 & 3;
    int vcol = (c8 >> 2) * 32 + (u & 1) * 16 + (u >> 1) * 4;   // sigma-permuted base

    uint4 kreg[2], vreg[2];

    // prologue: panel 0
    for (int p = 0; p < 2; ++p) {
        kreg[p] = *(const uint4*)&Kp[(p * 32 + srow) * 64 + scol];
        vreg[p] = *(const uint4*)&Vp[(p * 32 + srow) * 2048 + scol];
    }
    for (int p = 0; p < 2; ++p) {
        *(uint4*)&Ks[0][(p * 32 + srow) * 72 + scol] = kreg[p];
        ushort_t* vb = &Vs[0][(p * 32 + srow) * 72 + vcol];
        *(uint2*)vb = make_uint2(vreg[p].x, vreg[p].y);
        *(uint2*)(vb + 8) = make_uint2(vreg[p].z, vreg[p].w);
    }
    __syncthreads();

    floatx4 o_acc[2][4];
    float lsum[2] = {0.f, 0.f};
    floatx4 z = {0.f, 0.f, 0.f, 0.f};
    for (int g = 0; g < 2; ++g)
        for (int m4 = 0; m4 < 4; ++m4) o_acc[g][m4] = z;

    for (int kt = 0; kt < 32; ++kt) {
        int cur = kt & 1;
        if (kt < 31) {
            for (int p = 0; p < 2; ++p) {
                kreg[p] = *(const uint4*)&Kp[((kt + 1) * 64 + p * 32 + srow) * 64 + scol];
                vreg[p] = *(const uint4*)&Vp[(p * 32 + srow) * 2048 + (kt + 1) * 64 + scol];
            }
        }

        const ushort_t* KsH = Ks[cur];
        const ushort_t* VsH = Vs[cur];

        // K A-frags
        bf16x8 ak[4][2];
        for (int m4 = 0; m4 < 4; ++m4)
            for (int ks = 0; ks < 2; ++ks)
                ak[m4][ks] = *(const bf16x8*)&KsH[(m4 * 16 + ln) * 72 + ks * 32 + quad * 8];

        // S^T = K Q^T
        floatx4 st[2][4];
        for (int g = 0; g < 2; ++g)
            for (int m4 = 0; m4 < 4; ++m4) {
                floatx4 s = z;
                s = __builtin_amdgcn_mfma_f32_16x16x32_bf16(ak[m4][0], bqf[g][0], s, 0, 0, 0);
                s = __builtin_amdgcn_mfma_f32_16x16x32_bf16(ak[m4][1], bqf[g][1], s, 0, 0, 0);
                st[g][m4] = s;
            }

        // P^T = 2^(S^T); per-lane column partial sums
        float pv[2][4][4];
        for (int g = 0; g < 2; ++g)
            for (int m4 = 0; m4 < 4; ++m4)
                for (int r = 0; r < 4; ++r) {
                    float e = __builtin_amdgcn_exp2f(st[g][m4][r]);
                    pv[g][m4][r] = e;
                    lsum[g] += e;
                }

        // V^T A-frags (pre-permuted, contiguous b128)
        bf16x8 av[4][2];
        for (int m4 = 0; m4 < 4; ++m4)
            for (int c = 0; c < 2; ++c)
                av[m4][c] = *(const bf16x8*)&VsH[(m4 * 16 + ln) * 72 + c * 32 + quad * 8];

        // Pack P^T B-frags (sigma order) and accumulate O^T
        for (int g = 0; g < 2; ++g) {
            bf16x8 bp[2];
            for (int c = 0; c < 2; ++c) {
                bf16x8 b;
                b[0] = (__bf16)pv[g][2 * c][0];
                b[1] = (__bf16)pv[g][2 * c][1];
                b[2] = (__bf16)pv[g][2 * c][2];
                b[3] = (__bf16)pv[g][2 * c][3];
                b[4] = (__bf16)pv[g][2 * c + 1][0];
                b[5] = (__bf16)pv[g][2 * c + 1][1];
                b[6] = (__bf16)pv[g][2 * c + 1][2];
                b[7] = (__bf16)pv[g][2 * c + 1][3];
                bp[c] = b;
            }
            for (int m4 = 0; m4 < 4; ++m4)
                for (int c = 0; c < 2; ++c)
                    o_acc[g][m4] = __builtin_amdgcn_mfma_f32_16x16x32_bf16(av[m4][c], bp[c], o_acc[g][m4], 0, 0, 0);
        }

        // write prefetched panel into the other buffer (its last readers were
        // in iter kt-1, separated by the barrier below from iter kt-1)
        if (kt < 31) {
            int nxt = cur ^ 1;
            for (int p = 0; p < 2; ++p) {
                *(uint4*)&Ks[nxt][(p * 32 + srow) * 72 + scol] = kreg[p];
                ushort_t* vb = &Vs[nxt][(p * 32 + srow) * 72 + vcol];
                *(uint2*)vb = make_uint2(vreg[p].x, vreg[p].y);
                *(uint2*)(vb + 8) = make_uint2(vreg[p].z, vreg[p].w);
            }
        }
        __syncthreads();
    }

    // column sums: combine the 4 quads (lane&15 preserved)
    for (int g = 0; g < 2; ++g) {
        lsum[g] += __shfl_xor(lsum[g], 16);
        lsum[g] += __shfl_xor(lsum[g], 32);
    }

    int b = bh / 12, h = bh % 12;
    for (int g = 0; g < 2; ++g) {
        float inv = 1.f / lsum[g];
        int token = b * 2048 + q0 + g * 16 + ln;
        for (int m4 = 0; m4 < 4; ++m4)
            for (int r = 0; r < 4; ++r)
                Ob[token * 768 + h * 64 + m4 * 16 + quad * 4 + r] = f2bf(o_acc[g][m4][r] * inv);
    }
}

// ---------------------------------------------------------------- output projection (fp32 out, m97-style)
__global__ __launch_bounds__(256) void gemm_out(
    const ushort_t* __restrict__ A, const ushort_t* __restrict__ Bt,
    const float* __restrict__ bias, float* __restrict__ out) {
    __shared__ ushort_t As[128 * 64];
    __shared__ ushort_t Bs[128 * 64];
    int tid = threadIdx.x;
    int m0 = blockIdx.x * 128;
    int n0 = blockIdx.y * 128;

    int wave = tid >> 6;
    int lane = tid & 63;
    int ln = tid & 15;
    int quad = (tid >> 4) & 3;
    int wm = (wave & 1) * 64;
    int wn = (wave >> 1) * 64;
    int lr = lane >> 3;
    int lc = (lane & 7) * 8;

    floatx4 acc[4][4];
    floatx4 z = {0.f, 0.f, 0.f, 0.f};
    for (int i = 0; i < 4; ++i)
        for (int j = 0; j < 4; ++j) acc[i][j] = z;

    for (int kt = 0; kt < 12; ++kt) {
        int k0 = kt * 64;
        __syncthreads();
        for (int i = 0; i < 4; ++i) {
            int c = wave * 4 + i;
            int row = c * 8 + lr;
            gload16(&A[(m0 + row) * 768 + k0 + lc], &As[c * 512]);
            gload16(&Bt[(n0 + row) * 768 + k0 + lc], &Bs[c * 512]);
        }
        __syncthreads();
        for (int ks = 0; ks < 2; ++ks) {
            bf16x8 a[4], b[4];
            for (int i = 0; i < 4; ++i)
                a[i] = *(const bf16x8*)&As[(wm + i * 16 + ln) * 64 + ks * 32 + quad * 8];
            for (int j = 0; j < 4; ++j)
                b[j] = *(const bf16x8*)&Bs[(wn + j * 16 + ln) * 64 + ks * 32 + quad * 8];
            for (int i = 0; i < 4; ++i)
                for (int j = 0; j < 4; ++j)
                    acc[i][j] = __builtin_amdgcn_mfma_f32_16x16x32_bf16(a[i], b[j], acc[i][j], 0, 0, 0);
        }
    }

    for (int i = 0; i < 4; ++i) {
        for (int j = 0; j < 4; ++j) {
            int gn = n0 + wn + j * 16 + ln;
            float bia = bias[gn];
            for (int r = 0; r < 4; ++r) {
                int gm = m0 + wm + i * 16 + quad * 4 + r;
                out[gm * 768 + gn] = acc[i][j][r] + bia;
            }
        }
    }
}

extern "C" void kernel_launch(void* const* d_in, const int* in_sizes, int n_in,
                              void* d_out, int out_size, void* d_ws, size_t ws_size,
                              hipStream_t stream) {
    const float* x  = (const float*)d_in[0];
    const float* Wq = (const float*)d_in[1];
    const float* bq = (const float*)d_in[2];
    const float* Wk = (const float*)d_in[3];
    const float* bk = (const float*)d_in[4];
    const float* Wv = (const float*)d_in[5];
    const float* bv = (const float*)d_in[6];
    const float* Wo = (const float*)d_in[7];
    const float* bo = (const float*)d_in[8];

    const int NTOK = 4 * 2048;        // 8192
    const int NELT = NTOK * 768;      // 6291456
    const int WELT = 768 * 768;       // 589824

    ushort_t* xbf = (ushort_t*)d_ws;
    ushort_t* Tq  = xbf + NELT;
    ushort_t* Tk  = Tq + WELT;
    ushort_t* Tv  = Tk + WELT;
    ushort_t* To  = Tv + WELT;
    ushort_t* Qb  = To + WELT;
    ushort_t* Kb  = Qb + NELT;
    ushort_t* Vtb = Kb + NELT;
    ushort_t* Ob  = Vtb + NELT;

    cast_x_kernel<<<NELT / 1024, 256, 0, stream>>>(x, xbf);
    wt_kernel<<<dim3(24, 24, 4), dim3(32, 8), 0, stream>>>(Wq, Wk, Wv, Wo, Tq, Tk, Tv, To);
    gemm_qkv<<<dim3(64, 18), 256, 0, stream>>>(xbf, Tq, Tk, Tv, bq, bk, bv, Qb, Kb, Vtb);
    attn_kernel<<<dim3(16, 48), 256, 0, stream>>>(Qb, Kb, Vtb, Ob);
    gemm_out<<<dim3(64, 6), 256, 0, stream>>>(Ob, To, bo, (float*)d_out);
}